// Round 3
// baseline (766.666 us; speedup 1.0000x reference)
//
#include <hip/hip_runtime.h>
#include <hip/hip_bf16.h>

// EdgePredictor: gather-concat -> Linear(320->256) -> BatchNorm(train) ->
// Linear(256->8) -> LogSoftmax.
//
// All float tensors are FP32 (per reference setup_inputs); output FP32.
// Indices may be int32 (harness doc) or int64 (reference) -> runtime detect.
//
// Algebra (z never materialized):
//   logits = h @ M^T + C,  M = W2*diag(g')*W1 (8x320),  g' = gamma*rsqrt(var+eps)
//   C = b2 + W2 . (g'*b1 + beta - mu*g')
// Pass P: convert W1 -> bf16 (ws) for MFMA.
// Pass A: gather + GEMM1 (f32->bf16 staged in LDS), column sum/sumsq only.
// Pass B: fold stats into M (bf16, padded to 16 rows) and C.
// Pass C: gather + h@M^T (MFMA, N=16 padded) + log-softmax, f32 out.
// ws use: ~204 KB.

#define N_EDGES 800000

typedef __attribute__((ext_vector_type(8))) short short8;
typedef __attribute__((ext_vector_type(4))) float f32x4;

// ws layout (bytes)
#define WS_SUM  0        // 16 slots x 256 f32 = 16384
#define WS_SQ   16384    // 16 slots x 256 f32 = 16384
#define WS_CVEC 32768    // 16 f32
#define WS_FLAG 32832    // 1 int (1 = indices are int64)
#define WS_M    33280    // 16 x 320 bf16 = 10240
#define WS_W1B  43520    // 256 x 320 bf16 = 163840  (end ~207 KB)

__device__ __forceinline__ ushort f2bf(float f) {
    union { float f; unsigned int u; } x; x.f = f;
    unsigned int r = x.u + 0x7FFFu + ((x.u >> 16) & 1u);   // RNE
    return (ushort)(r >> 16);
}

__device__ __forceinline__ short8 cvt8(const float* __restrict__ p) {
    short8 r;
    #pragma unroll
    for (int i = 0; i < 8; i++) r[i] = (short)f2bf(p[i]);
    return r;
}

// -------- detect index width: int64 iff all sampled high words are zero -----
__global__ void detect_kernel(const int* __restrict__ src,
                              const int* __restrict__ dst, int* flag) {
    int t = threadIdx.x;                    // 64 threads = 1 wave
    int v = src[2 * t + 1] | dst[2 * t + 1];
    #pragma unroll
    for (int o = 32; o >= 1; o >>= 1) v |= __shfl_xor(v, o);
    if (t == 0) *flag = (v == 0) ? 1 : 0;
}

// -------- prep: W1 f32 -> bf16 --------
__global__ __launch_bounds__(256) void prep_kernel(const float* __restrict__ W1,
                                                   ushort* __restrict__ W1b) {
    const int i = (blockIdx.x * 256 + threadIdx.x) * 4;   // 81920 elems / 4
    const float4 v = *(const float4*)(W1 + i);
    ushort4 o;
    o.x = f2bf(v.x); o.y = f2bf(v.y); o.z = f2bf(v.z); o.w = f2bf(v.w);
    *(ushort4*)(W1b + i) = o;
}

// ---------------- Kernel A: gather + GEMM1 + column stats ----------------
// grid 12500, block 256 (4 waves). Tile: 64 edges x 256 cols, K=320 in 10x32.
__global__ __launch_bounds__(256) void gemm1_stats_kernel(
    const float* __restrict__ nf, const float* __restrict__ ef,
    const int* __restrict__ src, const int* __restrict__ dst,
    const ushort* __restrict__ W1b, const int* __restrict__ flag,
    float* __restrict__ g_sum, float* __restrict__ g_sq)
{
    // A-tile 64 rows x 32 cols bf16, row stride 40 elems (80 B)
    __shared__ ushort a_lds[64 * 40];
    __shared__ float s_sum[256];
    __shared__ float s_sq[256];

    const int t    = threadIdx.x;
    const int lane = t & 63;
    const int wave = t >> 6;
    const int quad = lane >> 4;
    const int l15  = lane & 15;

    s_sum[t] = 0.f; s_sq[t] = 0.f;

    const int wide = *flag;
    // staging: thread t handles row r = t>>2, 8-elem f32 chunk (t&3)
    const int r = t >> 2, chunk = t & 3;
    const long e  = (long)blockIdx.x * 64 + r;
    const long ei = e << wide;
    const int si = src[ei], di = dst[ei];
    const float* pe = ef + e * 64 + chunk * 8;
    const float* ps = nf + (long)si * 128 + chunk * 8;
    const float* pd = nf + (long)di * 128 + chunk * 8;

    f32x4 acc[4][4];   // [mb][in]: rows mb*16.., cols wave*64 + in*16..
    #pragma unroll
    for (int a = 0; a < 4; a++)
        #pragma unroll
        for (int b = 0; b < 4; b++) acc[a][b] = (f32x4){0.f, 0.f, 0.f, 0.f};

    // B-frag: lane reads W1b[col][k..k+8) (row-major [256][320])
    const ushort* wbase = W1b + (wave * 64 + l15) * 320 + quad * 8;

    #pragma unroll
    for (int ks = 0; ks < 10; ks++) {
        const int k0 = ks * 32;
        // concat segment uniform per ks (boundaries at 64, 192)
        const float* p = (ks < 2) ? (pe + k0)
                       : (ks < 6) ? (ps + (k0 - 64))
                                  : (pd + (k0 - 192));
        short8 stg = cvt8(p);
        __syncthreads();                       // prev iter's LDS reads done
        *(short8*)&a_lds[r * 40 + chunk * 8] = stg;
        __syncthreads();

        short8 bfr[4];
        #pragma unroll
        for (int in = 0; in < 4; in++)
            bfr[in] = *(const short8*)(wbase + in * 16 * 320 + k0);
        #pragma unroll
        for (int mb = 0; mb < 4; mb++) {
            short8 afr = *(const short8*)&a_lds[(mb * 16 + l15) * 40 + quad * 8];
            #pragma unroll
            for (int in = 0; in < 4; in++)
                acc[mb][in] = __builtin_amdgcn_mfma_f32_16x16x32_bf16(
                    afr, bfr[in], acc[mb][in], 0, 0, 0);
        }
    }

    // Stats on acc = z - b1 (b1 shift handled in fold; var shift-invariant).
    // C/D layout: col = lane&15, row = quad*4 + reg.
    #pragma unroll
    for (int in = 0; in < 4; in++) {
        const int col = wave * 64 + in * 16 + l15;
        float s = 0.f, q = 0.f;
        #pragma unroll
        for (int mb = 0; mb < 4; mb++) {
            #pragma unroll
            for (int j = 0; j < 4; j++) {
                float v = acc[mb][in][j];
                s += v; q += v * v;
            }
        }
        s += __shfl_xor(s, 16); s += __shfl_xor(s, 32);
        q += __shfl_xor(q, 16); q += __shfl_xor(q, 32);
        if (quad == 0) { atomicAdd(&s_sum[col], s); atomicAdd(&s_sq[col], q); }
    }
    __syncthreads();
    const int slot = blockIdx.x & 15;
    atomicAdd(&g_sum[slot * 256 + t], s_sum[t]);
    atomicAdd(&g_sq[slot * 256 + t], s_sq[t]);
}

// ---------------- Kernel B: fold stats into M and C ----------------
__global__ __launch_bounds__(256) void fold_kernel(
    const float* __restrict__ gamma, const float* __restrict__ beta,
    const float* __restrict__ W1, const float* __restrict__ b1,
    const float* __restrict__ W2, const float* __restrict__ b2,
    const float* __restrict__ g_sum, const float* __restrict__ g_sq,
    ushort* __restrict__ M, float* __restrict__ Cvec)
{
    __shared__ float a_sh[256][8];   // a[h][c] = W2[c][h] * g'[h]
    __shared__ float red[8];
    const int h = threadIdx.x;       // 256 threads = HID

    float ssum = 0.f, ssq = 0.f;
    #pragma unroll
    for (int s = 0; s < 16; s++) {
        ssum += g_sum[s * 256 + h];
        ssq  += g_sq[s * 256 + h];
    }
    const float invE   = 1.0f / (float)N_EDGES;
    const float mu_acc = ssum * invE;
    float var = ssq * invE - mu_acc * mu_acc;   // var(z), shift-invariant
    var = fmaxf(var, 0.f);
    const float b1v = b1[h];
    const float mu  = mu_acc + b1v;             // mu(z)
    const float g   = gamma[h] * rsqrtf(var + 1e-5f);
    const float sh  = b1v * g + beta[h] - mu * g;

    if (h < 8) red[h] = 0.f;
    __syncthreads();
    #pragma unroll
    for (int c = 0; c < 8; c++) {
        const float w = W2[c * 256 + h];
        a_sh[h][c] = w * g;
        atomicAdd(&red[c], w * sh);
    }
    __syncthreads();

    // M[c][k] = sum_h a[h][c] * W1[h][k]
    for (int k = h; k < 320; k += 256) {
        float m[8] = {0.f, 0.f, 0.f, 0.f, 0.f, 0.f, 0.f, 0.f};
        for (int hh = 0; hh < 256; hh++) {
            const float w1 = W1[hh * 320 + k];
            #pragma unroll
            for (int c = 0; c < 8; c++) m[c] += a_sh[hh][c] * w1;
        }
        #pragma unroll
        for (int c = 0; c < 8; c++) M[c * 320 + k] = f2bf(m[c]);
        #pragma unroll
        for (int c = 8; c < 16; c++) M[c * 320 + k] = 0;   // pad rows
    }
    if (h < 8)       Cvec[h] = b2[h] + red[h];
    else if (h < 16) Cvec[h] = 0.f;
}

// ---------------- Kernel C: gather + h@M^T + log-softmax ----------------
// grid 3125, block 256 (4 waves); wave: 64 edges x 16 cols (8 valid classes).
__global__ __launch_bounds__(256) void out_kernel(
    const float* __restrict__ nf, const float* __restrict__ ef,
    const int* __restrict__ src, const int* __restrict__ dst,
    const int* __restrict__ flag, const ushort* __restrict__ M,
    const float* __restrict__ Cvec, float* __restrict__ out)
{
    const int t    = threadIdx.x;
    const int lane = t & 63;
    const int wave = t >> 6;
    const int quad = lane >> 4;
    const int l15  = lane & 15;
    const int wide = *flag;
    const long eb  = (long)blockIdx.x * 256 + wave * 64;

    const float* pe[4]; const float* ps[4]; const float* pd[4];
    #pragma unroll
    for (int mb = 0; mb < 4; mb++) {
        const long e  = eb + mb * 16 + l15;
        const long ei = e << wide;
        const int si = src[ei], di = dst[ei];
        pe[mb] = ef + e * 64;
        ps[mb] = nf + (long)si * 128;
        pd[mb] = nf + (long)di * 128;
    }

    f32x4 acc[4];
    #pragma unroll
    for (int mb = 0; mb < 4; mb++) acc[mb] = (f32x4){0.f, 0.f, 0.f, 0.f};

    const ushort* bbase = M + l15 * 320 + quad * 8;

    #pragma unroll
    for (int ks = 0; ks < 10; ks++) {
        const int k0 = ks * 32;
        short8 bfr = *(const short8*)(bbase + k0);
        const int koff = k0 + quad * 8;       // lane's absolute k
        #pragma unroll
        for (int mb = 0; mb < 4; mb++) {
            const float* p = (ks < 2) ? (pe[mb] + koff)
                           : (ks < 6) ? (ps[mb] + (koff - 64))
                                      : (pd[mb] + (koff - 192));
            short8 afr = cvt8(p);
            acc[mb] = __builtin_amdgcn_mfma_f32_16x16x32_bf16(afr, bfr, acc[mb], 0, 0, 0);
        }
    }

    const float bv = Cvec[l15];
    #pragma unroll
    for (int mb = 0; mb < 4; mb++) {
        #pragma unroll
        for (int j = 0; j < 4; j++) {
            float x = acc[mb][j] + bv;
            // softmax over 8 classes in lanes (quad*16) + 0..7
            float m = x;
            m = fmaxf(m, __shfl_xor(m, 1));
            m = fmaxf(m, __shfl_xor(m, 2));
            m = fmaxf(m, __shfl_xor(m, 4));
            float sx = __expf(x - m);
            sx += __shfl_xor(sx, 1);
            sx += __shfl_xor(sx, 2);
            sx += __shfl_xor(sx, 4);
            const float o = x - m - __logf(sx);
            if (l15 < 8)
                out[(eb + mb * 16 + quad * 4 + j) * 8 + l15] = o;
        }
    }
}

extern "C" void kernel_launch(void* const* d_in, const int* in_sizes, int n_in,
                              void* d_out, int out_size, void* d_ws, size_t ws_size,
                              hipStream_t stream) {
    const float* nf    = (const float*)d_in[0];  // n_feats   50000x128 f32
    const float* ef    = (const float*)d_in[1];  // edge_feats 800000x64 f32
    const int*   src   = (const int*)d_in[2];
    const int*   dst   = (const int*)d_in[3];
    const float* W1    = (const float*)d_in[4];  // 256x320
    const float* b1    = (const float*)d_in[5];
    const float* gamma = (const float*)d_in[6];
    const float* beta  = (const float*)d_in[7];
    const float* W2    = (const float*)d_in[8];  // 8x256
    const float* b2    = (const float*)d_in[9];

    char*   ws    = (char*)d_ws;
    float*  g_sum = (float*)(ws + WS_SUM);
    float*  g_sq  = (float*)(ws + WS_SQ);
    float*  Cvec  = (float*)(ws + WS_CVEC);
    int*    flag  = (int*)(ws + WS_FLAG);
    ushort* M     = (ushort*)(ws + WS_M);
    ushort* W1b   = (ushort*)(ws + WS_W1B);

    hipMemsetAsync(ws, 0, 33280, stream);             // zero stats slots
    detect_kernel<<<1, 64, 0, stream>>>(src, dst, flag);
    prep_kernel<<<80, 256, 0, stream>>>(W1, W1b);     // 81920 elems
    gemm1_stats_kernel<<<N_EDGES / 64, 256, 0, stream>>>(nf, ef, src, dst, W1b,
                                                         flag, g_sum, g_sq);
    fold_kernel<<<1, 256, 0, stream>>>(gamma, beta, W1, b1, W2, b2,
                                       g_sum, g_sq, M, Cvec);
    out_kernel<<<N_EDGES / 256, 256, 0, stream>>>(nf, ef, src, dst, flag, M,
                                                  Cvec, (float*)d_out);
}

// Round 4
// 698.589 us; speedup vs baseline: 1.0974x; 1.0974x over previous
//
#include <hip/hip_runtime.h>
#include <hip/hip_bf16.h>

// EdgePredictor: gather-concat -> Linear(320->256) -> BatchNorm(train) ->
// Linear(256->8) -> LogSoftmax.  All float tensors FP32; output FP32.
// Indices int32 or int64 -> runtime detect (1-wave probe).
//
// Algebra: logits = h @ M^T + C,  M = W2*diag(g')*W1 (8x320).
// Split along concat:  logits_e = ef_e @ Me^T + Ps[src_e] + Pd[dst_e] + C
//   Ps = nf @ Ms^T, Pd = nf @ Md^T  (50000x8 tables, 3.2 MB ws)
// Pass A: gather + GEMM1 for column sum/sumsq (5-deep register prefetch +
//         double-buffered LDS: load latency off the critical path).
// Pass B: fold stats into M (f32 + bf16 copies) and C.
// Pass P: node projection tables (sequential nf read).
// Pass C: ef-only GEMM (K=64, MFMA) + table lookups + log-softmax.
// Fallback (ws too small): round-3 gather out_kernel.

#define N_EDGES 800000
#define N_NODES 50000

typedef __attribute__((ext_vector_type(8))) short short8;
typedef __attribute__((ext_vector_type(4))) float f32x4;

// ws layout (bytes)
#define WS_SUM   0         // 16 slots x 256 f32 = 16384
#define WS_SQ    16384     // 16384
#define WS_CVEC  32768     // 16 f32
#define WS_FLAG  32832     // 1 int (pad to 33280)
#define WS_MBIG  33280     // 16 x 320 bf16 = 10240 (fallback path)
#define WS_MB    43520     // 16 x 64 bf16 = 2048 (edge part)
#define WS_MF    45568     // 8 x 320 f32 = 10240
#define WS_W1B   55808     // 256 x 320 bf16 = 163840 -> 219648
#define WS_PS    262144    // 50000 x 8 f32 + pad = 1600064
#define WS_PD    2097152   // 1600064 -> end 3697216
#define WS_FAST_NEED (4u << 20)

__device__ __forceinline__ ushort f2bf(float f) {
    union { float f; unsigned int u; } x; x.f = f;
    unsigned int r = x.u + 0x7FFFu + ((x.u >> 16) & 1u);   // RNE
    return (ushort)(r >> 16);
}
__device__ __forceinline__ short8 cvt8(const float* __restrict__ p) {
    short8 r;
    #pragma unroll
    for (int i = 0; i < 8; i++) r[i] = (short)f2bf(p[i]);
    return r;
}
__device__ __forceinline__ short8 cvtpair(uint4 a, uint4 b) {
    unsigned int v[8] = {a.x, a.y, a.z, a.w, b.x, b.y, b.z, b.w};
    short8 r;
    #pragma unroll
    for (int i = 0; i < 8; i++) {
        unsigned int u = v[i];
        unsigned int rr = u + 0x7FFFu + ((u >> 16) & 1u);
        r[i] = (short)(rr >> 16);
    }
    return r;
}

// -------- detect index width: int64 iff all sampled high words are zero ----
__global__ void detect_kernel(const int* __restrict__ src,
                              const int* __restrict__ dst, int* flag) {
    int t = threadIdx.x;
    int v = src[2 * t + 1] | dst[2 * t + 1];
    #pragma unroll
    for (int o = 32; o >= 1; o >>= 1) v |= __shfl_xor(v, o);
    if (t == 0) *flag = (v == 0) ? 1 : 0;
}

// -------- prep: W1 f32 -> bf16 --------
__global__ __launch_bounds__(256) void prep_kernel(const float* __restrict__ W1,
                                                   ushort* __restrict__ W1b) {
    const int i = (blockIdx.x * 256 + threadIdx.x) * 4;
    const float4 v = *(const float4*)(W1 + i);
    ushort4 o;
    o.x = f2bf(v.x); o.y = f2bf(v.y); o.z = f2bf(v.z); o.w = f2bf(v.w);
    *(ushort4*)(W1b + i) = o;
}

// ---------------- Kernel A: gather + GEMM1 + column stats ----------------
// grid 12500, block 256 (4 waves). Tile 64 edges x 256 cols, K=320 in 10x32.
// 5-slice register prefetch (40 VGPR) + double-buffered LDS (1 barrier/iter).
__global__ __launch_bounds__(256) void gemm1_stats_kernel(
    const float* __restrict__ nf, const float* __restrict__ ef,
    const int* __restrict__ src, const int* __restrict__ dst,
    const ushort* __restrict__ W1b, const int* __restrict__ flag,
    float* __restrict__ g_sum, float* __restrict__ g_sq)
{
    __shared__ ushort a_lds[2][64 * 40];   // 2 x 64 rows x 32 bf16, stride 40
    __shared__ float s_sum[256];
    __shared__ float s_sq[256];

    const int t    = threadIdx.x;
    const int lane = t & 63;
    const int wave = t >> 6;
    const int quad = lane >> 4;
    const int l15  = lane & 15;

    s_sum[t] = 0.f; s_sq[t] = 0.f;

    const int wide = *flag;
    const int r = t >> 2, chunk = t & 3;       // row, 8-f32 chunk
    const long e  = (long)blockIdx.x * 64 + r;
    const int si = src[e << wide], di = dst[e << wide];
    const float* pe = ef + e * 64 + chunk * 8;
    const float* ps = nf + (long)si * 128 + chunk * 8;
    const float* pd = nf + (long)di * 128 + chunk * 8;

    uint4 pre[10];                              // 5 slices x 2
    #pragma unroll
    for (int ks = 0; ks < 5; ks++) {            // slices 0..4 in flight
        const float* p = (ks < 2) ? (pe + ks * 32) : (ps + (ks * 32 - 64));
        pre[ks * 2]     = *(const uint4*)p;
        pre[ks * 2 + 1] = *(const uint4*)(p + 4);
    }
    *(short8*)&a_lds[0][r * 40 + chunk * 8] = cvtpair(pre[0], pre[1]);
    __syncthreads();

    f32x4 acc[4][4];
    #pragma unroll
    for (int a = 0; a < 4; a++)
        #pragma unroll
        for (int b = 0; b < 4; b++) acc[a][b] = (f32x4){0.f, 0.f, 0.f, 0.f};

    const ushort* wbase = W1b + (wave * 64 + l15) * 320 + quad * 8;

    #pragma unroll
    for (int ks = 0; ks < 10; ks++) {
        if (ks < 5) {                          // issue slice ks+5
            const int kn = ks + 5;
            const float* p = (kn < 6) ? (ps + (kn * 32 - 64))
                                      : (pd + (kn * 32 - 192));
            pre[(kn % 5) * 2]     = *(const uint4*)p;
            pre[(kn % 5) * 2 + 1] = *(const uint4*)(p + 4);
        }
        if (ks < 9) {                          // stage slice ks+1 -> other buf
            const int s = ((ks + 1) % 5) * 2;
            *(short8*)&a_lds[(ks + 1) & 1][r * 40 + chunk * 8] =
                cvtpair(pre[s], pre[s + 1]);
        }
        short8 bfr[4];
        #pragma unroll
        for (int in = 0; in < 4; in++)
            bfr[in] = *(const short8*)(wbase + in * 16 * 320 + ks * 32);
        #pragma unroll
        for (int mb = 0; mb < 4; mb++) {
            short8 afr = *(const short8*)
                &a_lds[ks & 1][(mb * 16 + l15) * 40 + quad * 8];
            #pragma unroll
            for (int in = 0; in < 4; in++)
                acc[mb][in] = __builtin_amdgcn_mfma_f32_16x16x32_bf16(
                    afr, bfr[in], acc[mb][in], 0, 0, 0);
        }
        __syncthreads();
    }

    // Stats on acc = z - b1 (b1 folded later; var shift-invariant).
    // C/D layout: col = lane&15, row = quad*4 + reg.
    #pragma unroll
    for (int in = 0; in < 4; in++) {
        const int col = wave * 64 + in * 16 + l15;
        float s = 0.f, q = 0.f;
        #pragma unroll
        for (int mb = 0; mb < 4; mb++)
            #pragma unroll
            for (int j = 0; j < 4; j++) {
                float v = acc[mb][in][j];
                s += v; q += v * v;
            }
        s += __shfl_xor(s, 16); s += __shfl_xor(s, 32);
        q += __shfl_xor(q, 16); q += __shfl_xor(q, 32);
        if (quad == 0) { atomicAdd(&s_sum[col], s); atomicAdd(&s_sq[col], q); }
    }
    __syncthreads();
    const int slot = blockIdx.x & 15;
    atomicAdd(&g_sum[slot * 256 + t], s_sum[t]);
    atomicAdd(&g_sq[slot * 256 + t], s_sq[t]);
}

// ---------------- Kernel B: fold stats into M / C ----------------
__global__ __launch_bounds__(256) void fold_kernel(
    const float* __restrict__ gamma, const float* __restrict__ beta,
    const float* __restrict__ W1, const float* __restrict__ b1,
    const float* __restrict__ W2, const float* __restrict__ b2,
    const float* __restrict__ g_sum, const float* __restrict__ g_sq,
    ushort* __restrict__ Mbig, ushort* __restrict__ Mb,
    float* __restrict__ Mf, float* __restrict__ Cvec)
{
    __shared__ float a_sh[256][8];   // a[h][c] = W2[c][h] * g'[h]
    __shared__ float red[8];
    const int h = threadIdx.x;

    float ssum = 0.f, ssq = 0.f;
    #pragma unroll
    for (int s = 0; s < 16; s++) {
        ssum += g_sum[s * 256 + h];
        ssq  += g_sq[s * 256 + h];
    }
    const float invE   = 1.0f / (float)N_EDGES;
    const float mu_acc = ssum * invE;
    float var = ssq * invE - mu_acc * mu_acc;
    var = fmaxf(var, 0.f);
    const float b1v = b1[h];
    const float mu  = mu_acc + b1v;
    const float g   = gamma[h] * rsqrtf(var + 1e-5f);
    const float sh  = b1v * g + beta[h] - mu * g;

    if (h < 8) red[h] = 0.f;
    __syncthreads();
    #pragma unroll
    for (int c = 0; c < 8; c++) {
        const float w = W2[c * 256 + h];
        a_sh[h][c] = w * g;
        atomicAdd(&red[c], w * sh);
    }
    __syncthreads();

    for (int k = h; k < 320; k += 256) {
        float m[8] = {0.f, 0.f, 0.f, 0.f, 0.f, 0.f, 0.f, 0.f};
        for (int hh = 0; hh < 256; hh++) {
            const float w1 = W1[hh * 320 + k];
            #pragma unroll
            for (int c = 0; c < 8; c++) m[c] += a_sh[hh][c] * w1;
        }
        #pragma unroll
        for (int c = 0; c < 8; c++) {
            Mf[c * 320 + k]   = m[c];
            Mbig[c * 320 + k] = f2bf(m[c]);
            if (k < 64) Mb[c * 64 + k] = f2bf(m[c]);
        }
        #pragma unroll
        for (int c = 8; c < 16; c++) {
            Mbig[c * 320 + k] = 0;
            if (k < 64) Mb[c * 64 + k] = 0;
        }
    }
    if (h < 8)       Cvec[h] = b2[h] + red[h];
    else if (h < 16) Cvec[h] = 0.f;
}

// ---------------- Kernel P: node projection tables ----------------
// Ps[n][c] = nf[n] . Mf[c][64..192), Pd[n][c] = nf[n] . Mf[c][192..320)
__global__ __launch_bounds__(256) void nodeproj_kernel(
    const float* __restrict__ nf, const float* __restrict__ Mf,
    float* __restrict__ Ps, float* __restrict__ Pd)
{
    __shared__ float Ms[8][128];
    __shared__ float Md[8][128];
    const int t = threadIdx.x;
    #pragma unroll
    for (int i = 0; i < 4; i++) {
        const int f = t + i * 256;               // 1024 elems each table
        Ms[f >> 7][f & 127] = Mf[(f >> 7) * 320 + 64  + (f & 127)];
        Md[f >> 7][f & 127] = Mf[(f >> 7) * 320 + 192 + (f & 127)];
    }
    __syncthreads();
    const int n = blockIdx.x * 256 + t;
    if (n >= N_NODES) return;
    float as[8] = {0,0,0,0,0,0,0,0}, ad[8] = {0,0,0,0,0,0,0,0};
    for (int k = 0; k < 128; k += 4) {
        const float4 v = *(const float4*)(nf + (long)n * 128 + k);
        #pragma unroll
        for (int c = 0; c < 8; c++) {
            const float4 ms = *(const float4*)&Ms[c][k];
            const float4 md = *(const float4*)&Md[c][k];
            as[c] += v.x * ms.x + v.y * ms.y + v.z * ms.z + v.w * ms.w;
            ad[c] += v.x * md.x + v.y * md.y + v.z * md.z + v.w * md.w;
        }
    }
    #pragma unroll
    for (int c = 0; c < 8; c++) {
        Ps[n * 8 + c] = as[c];
        Pd[n * 8 + c] = ad[c];
    }
}

// ---------------- Kernel C (fast): ef GEMM + tables + log-softmax ----------
// grid 3125, block 256 (4 waves); wave: 64 edges x 16 cols (8 valid).
__global__ __launch_bounds__(256) void edge_out_kernel(
    const float* __restrict__ ef, const int* __restrict__ src,
    const int* __restrict__ dst, const int* __restrict__ flag,
    const ushort* __restrict__ Mb, const float* __restrict__ Ps,
    const float* __restrict__ Pd, const float* __restrict__ Cvec,
    float* __restrict__ out)
{
    const int t    = threadIdx.x;
    const int lane = t & 63;
    const int wave = t >> 6;
    const int quad = lane >> 4;
    const int l15  = lane & 15;
    const int wide = *flag;
    const long eb  = (long)blockIdx.x * 256 + wave * 64;

    f32x4 acc[4];
    #pragma unroll
    for (int mb = 0; mb < 4; mb++) acc[mb] = (f32x4){0.f, 0.f, 0.f, 0.f};

    const ushort* bbase = Mb + l15 * 64 + quad * 8;
    #pragma unroll
    for (int ks = 0; ks < 2; ks++) {
        short8 bfr = *(const short8*)(bbase + ks * 32);
        #pragma unroll
        for (int mb = 0; mb < 4; mb++) {
            const float* p = ef + (eb + mb * 16 + l15) * 64 + ks * 32 + quad * 8;
            uint4 a = *(const uint4*)p;
            uint4 b = *(const uint4*)(p + 4);
            acc[mb] = __builtin_amdgcn_mfma_f32_16x16x32_bf16(
                cvtpair(a, b), bfr, acc[mb], 0, 0, 0);
        }
    }

    const float bv = Cvec[l15];
    #pragma unroll
    for (int mb = 0; mb < 4; mb++) {
        #pragma unroll
        for (int j = 0; j < 4; j++) {
            const long e = eb + mb * 16 + quad * 4 + j;
            float pv = 0.f;
            if (l15 < 8) {
                const long ei = e << wide;
                const int sidx = src[ei], didx = dst[ei];
                pv = Ps[sidx * 8 + l15] + Pd[didx * 8 + l15];
            }
            float x = acc[mb][j] + bv + pv;
            float m = x;
            m = fmaxf(m, __shfl_xor(m, 1));
            m = fmaxf(m, __shfl_xor(m, 2));
            m = fmaxf(m, __shfl_xor(m, 4));
            float sx = __expf(x - m);
            sx += __shfl_xor(sx, 1);
            sx += __shfl_xor(sx, 2);
            sx += __shfl_xor(sx, 4);
            const float o = x - m - __logf(sx);
            if (l15 < 8) out[e * 8 + l15] = o;
        }
    }
}

// ---------------- Kernel C (fallback): full gather (round-3) --------------
__global__ __launch_bounds__(256) void out_kernel(
    const float* __restrict__ nf, const float* __restrict__ ef,
    const int* __restrict__ src, const int* __restrict__ dst,
    const int* __restrict__ flag, const ushort* __restrict__ M,
    const float* __restrict__ Cvec, float* __restrict__ out)
{
    const int t    = threadIdx.x;
    const int lane = t & 63;
    const int wave = t >> 6;
    const int quad = lane >> 4;
    const int l15  = lane & 15;
    const int wide = *flag;
    const long eb  = (long)blockIdx.x * 256 + wave * 64;

    const float* pe[4]; const float* ps[4]; const float* pd[4];
    #pragma unroll
    for (int mb = 0; mb < 4; mb++) {
        const long e  = eb + mb * 16 + l15;
        const int si = src[e << wide], di = dst[e << wide];
        pe[mb] = ef + e * 64;
        ps[mb] = nf + (long)si * 128;
        pd[mb] = nf + (long)di * 128;
    }
    f32x4 acc[4];
    #pragma unroll
    for (int mb = 0; mb < 4; mb++) acc[mb] = (f32x4){0.f, 0.f, 0.f, 0.f};
    const ushort* bbase = M + l15 * 320 + quad * 8;
    #pragma unroll
    for (int ks = 0; ks < 10; ks++) {
        const int k0 = ks * 32;
        short8 bfr = *(const short8*)(bbase + k0);
        const int koff = k0 + quad * 8;
        #pragma unroll
        for (int mb = 0; mb < 4; mb++) {
            const float* p = (ks < 2) ? (pe[mb] + koff)
                           : (ks < 6) ? (ps[mb] + (koff - 64))
                                      : (pd[mb] + (koff - 192));
            acc[mb] = __builtin_amdgcn_mfma_f32_16x16x32_bf16(
                cvt8(p), bfr, acc[mb], 0, 0, 0);
        }
    }
    const float bv = Cvec[l15];
    #pragma unroll
    for (int mb = 0; mb < 4; mb++)
        #pragma unroll
        for (int j = 0; j < 4; j++) {
            float x = acc[mb][j] + bv;
            float m = x;
            m = fmaxf(m, __shfl_xor(m, 1));
            m = fmaxf(m, __shfl_xor(m, 2));
            m = fmaxf(m, __shfl_xor(m, 4));
            float sx = __expf(x - m);
            sx += __shfl_xor(sx, 1);
            sx += __shfl_xor(sx, 2);
            sx += __shfl_xor(sx, 4);
            const float o = x - m - __logf(sx);
            if (l15 < 8)
                out[(eb + mb * 16 + quad * 4 + j) * 8 + l15] = o;
        }
}

extern "C" void kernel_launch(void* const* d_in, const int* in_sizes, int n_in,
                              void* d_out, int out_size, void* d_ws, size_t ws_size,
                              hipStream_t stream) {
    const float* nf    = (const float*)d_in[0];
    const float* ef    = (const float*)d_in[1];
    const int*   src   = (const int*)d_in[2];
    const int*   dst   = (const int*)d_in[3];
    const float* W1    = (const float*)d_in[4];
    const float* b1    = (const float*)d_in[5];
    const float* gamma = (const float*)d_in[6];
    const float* beta  = (const float*)d_in[7];
    const float* W2    = (const float*)d_in[8];
    const float* b2    = (const float*)d_in[9];

    char*   ws    = (char*)d_ws;
    float*  g_sum = (float*)(ws + WS_SUM);
    float*  g_sq  = (float*)(ws + WS_SQ);
    float*  Cvec  = (float*)(ws + WS_CVEC);
    int*    flag  = (int*)(ws + WS_FLAG);
    ushort* Mbig  = (ushort*)(ws + WS_MBIG);
    ushort* Mb    = (ushort*)(ws + WS_MB);
    float*  Mf    = (float*)(ws + WS_MF);
    ushort* W1b   = (ushort*)(ws + WS_W1B);
    float*  Ps    = (float*)(ws + WS_PS);
    float*  Pd    = (float*)(ws + WS_PD);
    float*  out   = (float*)d_out;

    hipMemsetAsync(ws, 0, 33280, stream);
    detect_kernel<<<1, 64, 0, stream>>>(src, dst, flag);
    prep_kernel<<<80, 256, 0, stream>>>(W1, W1b);
    gemm1_stats_kernel<<<N_EDGES / 64, 256, 0, stream>>>(nf, ef, src, dst, W1b,
                                                         flag, g_sum, g_sq);
    fold_kernel<<<1, 256, 0, stream>>>(gamma, beta, W1, b1, W2, b2,
                                       g_sum, g_sq, Mbig, Mb, Mf, Cvec);
    if (ws_size >= WS_FAST_NEED) {
        nodeproj_kernel<<<(N_NODES + 255) / 256, 256, 0, stream>>>(nf, Mf, Ps, Pd);
        edge_out_kernel<<<N_EDGES / 256, 256, 0, stream>>>(ef, src, dst, flag,
                                                           Mb, Ps, Pd, Cvec, out);
    } else {
        out_kernel<<<N_EDGES / 256, 256, 0, stream>>>(nf, ef, src, dst, flag,
                                                      Mbig, Cvec, out);
    }
}